// Round 4
// baseline (180.016 us; speedup 1.0000x reference)
//
#include <hip/hip_runtime.h>

#define N_B   64
#define T_S   32
#define DIM   12288          // 3*64*64
#define ROWS  2048           // N_B*T_S
#define NCOL  12             // used GEMM columns (3 obj * 4)
#define RPB   4              // rows per block
#define KSPL  4              // split-K factor
#define KSEG  (DIM / KSPL)   // 3072
#define TILE  1024           // k per tile (256 thr * float4)
#define NTILE (KSEG / TILE)  // 3

typedef float f4 __attribute__((ext_vector_type(4)));   // native vector: OK for nontemporal builtin

// ---------------- Kernel 0: transpose used W columns -> Wt[c][k] -----------
__global__ __launch_bounds__(256) void k_tw(const float* __restrict__ W,
                                            float* __restrict__ Wt) {
    const int idx = blockIdx.x * 256 + threadIdx.x;   // 0 .. 147455
    const int c   = idx / DIM;
    const int k   = idx - c * DIM;
    const int cm  = ((c >> 2) << 3) | (c & 3);
    Wt[idx] = W[k * 24 + cm];
}

// ---------------- Kernel 1: split-K coalesced skinny GEMM ------------------
// Grid: 2048 blocks = 512 row-groups x 4 k-segments. 256 threads span k
// (contiguous float4/lane). x nontemporal (read-once) so Wt stays in L2.
__global__ __launch_bounds__(256) void k_gemm(const float* __restrict__ x,
                                              const float* __restrict__ Wt,
                                              float* __restrict__ part) {
    const int rb  = blockIdx.x >> 2;       // row group
    const int sg  = blockIdx.x & 3;        // k segment
    const int r0  = rb * RPB;
    const int k00 = sg * KSEG;
    const int tid = threadIdx.x;

    float acc[RPB][NCOL];
#pragma unroll
    for (int r = 0; r < RPB; ++r)
#pragma unroll
        for (int c = 0; c < NCOL; ++c) acc[r][c] = 0.f;

#pragma unroll
    for (int t = 0; t < NTILE; ++t) {
        const int kb = k00 + t * TILE + tid * 4;
        f4 wv[NCOL];
#pragma unroll
        for (int c = 0; c < NCOL; ++c)
            wv[c] = *(const f4*)(Wt + (size_t)c * DIM + kb);
        f4 xv[RPB];
#pragma unroll
        for (int r = 0; r < RPB; ++r)
            xv[r] = __builtin_nontemporal_load(
                        (const f4*)(x + (size_t)(r0 + r) * DIM + kb));
#pragma unroll
        for (int r = 0; r < RPB; ++r)
#pragma unroll
            for (int c = 0; c < NCOL; ++c)
                acc[r][c] += xv[r][0] * wv[c][0] + xv[r][1] * wv[c][1] +
                             xv[r][2] * wv[c][2] + xv[r][3] * wv[c][3];
    }

    // wave butterfly reduction of all 48 accumulators
#pragma unroll
    for (int r = 0; r < RPB; ++r)
#pragma unroll
        for (int c = 0; c < NCOL; ++c) {
            float v = acc[r][c];
            v += __shfl_xor(v, 32, 64);
            v += __shfl_xor(v, 16, 64);
            v += __shfl_xor(v, 8, 64);
            v += __shfl_xor(v, 4, 64);
            v += __shfl_xor(v, 2, 64);
            v += __shfl_xor(v, 1, 64);
            acc[r][c] = v;
        }

    __shared__ float red[4][RPB * NCOL];
    const int wave = tid >> 6;
    const int lane = tid & 63;
    if (lane == 0) {
#pragma unroll
        for (int r = 0; r < RPB; ++r)
#pragma unroll
            for (int c = 0; c < NCOL; ++c)
                red[wave][r * NCOL + c] = acc[r][c];
    }
    __syncthreads();

    if (tid < RPB * NCOL) {
        const float s = red[0][tid] + red[1][tid] + red[2][tid] + red[3][tid];
        // part[sg][row*12+c], contiguous 48-float store per block
        part[(size_t)sg * (ROWS * NCOL) + (size_t)r0 * NCOL + tid] = s;
    }
}

// ---------------- Kernel 2: reduce split-K + bias + sigmoid constrain ------
__global__ __launch_bounds__(256) void k_reduce(const float* __restrict__ part,
                                                const float* __restrict__ b_enc,
                                                float* __restrict__ zbuf) {
    const int rc = blockIdx.x * 256 + threadIdx.x;    // 0..24575 = row*12+c
    float s = part[rc] + part[ROWS * NCOL + rc] +
              part[2 * ROWS * NCOL + rc] + part[3 * ROWS * NCOL + rc];

    const int c  = rc % NCOL;
    const int o  = c >> 2;
    const int cp = c & 3;
    s += b_enc[o * 8 + cp];
    const float sg = 1.f / (1.f + expf(-s));
    float v;
    if (cp == 0)      v = sg * 0.7f + 0.1f;
    else if (cp == 1) v = sg * 0.5f + 0.75f;
    else              v = (2.f * sg - 1.f) * 0.9f;
    zbuf[rc] = v;
}

// ---------------- Kernel 3: match + fix_supair + output --------------------
__global__ __launch_bounds__(64) void k_post(const float* __restrict__ zbuf,
                                             float* __restrict__ out) {
    __shared__ float z[T_S * NCOL];
    __shared__ float zm[T_S * NCOL];
    __shared__ float zf[T_S * NCOL];
    __shared__ int   perm[T_S];
    const int b   = blockIdx.x;
    const int tid = threadIdx.x;

#pragma unroll
    for (int i = 0; i < 6; ++i)
        z[tid + 64 * i] = zbuf[b * 384 + tid + 64 * i];
    __syncthreads();

    if (tid == 0) {
        float px0 = z[2],  py0 = z[3];
        float px1 = z[6],  py1 = z[7];
        float px2 = z[10], py2 = z[11];
        for (int t = 1; t < T_S; ++t) {
            const int base = t * 12;
            const float cx0 = z[base + 2],  cy0 = z[base + 3];
            const float cx1 = z[base + 6],  cy1 = z[base + 7];
            const float cx2 = z[base + 10], cy2 = z[base + 11];

            float dx, dy;
            dx = px0 - cx0; dy = py0 - cy0; const float e00 = dx * dx + dy * dy;
            dx = px0 - cx1; dy = py0 - cy1; const float e01 = dx * dx + dy * dy;
            dx = px0 - cx2; dy = py0 - cy2; const float e02 = dx * dx + dy * dy;
            dx = px1 - cx0; dy = py1 - cy0; const float e10 = dx * dx + dy * dy;
            dx = px1 - cx1; dy = py1 - cy1; const float e11 = dx * dx + dy * dy;
            dx = px1 - cx2; dy = py1 - cy2; const float e12 = dx * dx + dy * dy;
            dx = px2 - cx0; dy = py2 - cy0; const float e20 = dx * dx + dy * dy;
            dx = px2 - cx1; dy = py2 - cy1; const float e21 = dx * dx + dy * dy;
            dx = px2 - cx2; dy = py2 - cy2; const float e22 = dx * dx + dy * dy;

            auto amin3 = [](float a0, float a1, float a2) {
                int j = 0; float e = a0;
                if (a1 < e) { e = a1; j = 1; }
                if (a2 < e) { j = 2; }
                return j;
            };
            int i0 = amin3(e00, e01, e02);
            int i1 = amin3(e10, e11, e12);
            int i2 = amin3(e20, e21, e22);
            const bool ok = (i1 != i0) && (i2 != i1) && (i0 != i2);
            if (!ok) {
                float u0 = 0.f, u1 = 0.f, u2 = 0.f;
                i0 = amin3(e00, e01, e02);
                if (i0 == 0) u0 = 1.f; else if (i0 == 1) u1 = 1.f; else u2 = 1.f;
                i1 = amin3(e10 + u0 * 1e12f, e11 + u1 * 1e12f, e12 + u2 * 1e12f);
                if (i1 == 0) u0 = 1.f; else if (i1 == 1) u1 = 1.f; else u2 = 1.f;
                i2 = amin3(e20 + u0 * 1e12f, e21 + u1 * 1e12f, e22 + u2 * 1e12f);
            }
            perm[t] = i0 * 9 + i1 * 3 + i2;
            px0 = (i0 == 0) ? cx0 : (i0 == 1) ? cx1 : cx2;
            py0 = (i0 == 0) ? cy0 : (i0 == 1) ? cy1 : cy2;
            px1 = (i1 == 0) ? cx0 : (i1 == 1) ? cx1 : cx2;
            py1 = (i1 == 0) ? cy0 : (i1 == 1) ? cy1 : cy2;
            px2 = (i2 == 0) ? cx0 : (i2 == 1) ? cx1 : cx2;
            py2 = (i2 == 0) ? cy0 : (i2 == 1) ? cy1 : cy2;
        }
    }
    __syncthreads();

#pragma unroll
    for (int ii = 0; ii < 6; ++ii) {
        const int i  = tid + 64 * ii;
        const int t  = i / 12;
        const int j  = i - t * 12;
        const int k  = j >> 2;
        const int ch = j & 3;
        int p = k;
        if (t > 0) {
            const int code = perm[t];
            p = (k == 0) ? code / 9 : (k == 1) ? (code % 9) / 3 : code % 3;
        }
        zm[i] = z[t * 12 + p * 4 + ch];
    }
    __syncthreads();

#pragma unroll
    for (int ii = 0; ii < 6; ++ii) {
        const int i  = tid + 64 * ii;
        const int t  = i / 12;
        const int j  = i - t * 12;
        const int o  = j >> 2;
        const int cc = j & 1;
        const int mb = o * 4 + cc;
        const float pd = (t >= 1)  ? fabsf(zm[t * 12 + mb] - zm[(t - 1) * 12 + mb]) : 0.f;
        const float ad = (t <= 30) ? fabsf(zm[(t + 1) * 12 + mb] - zm[t * 12 + mb]) : 0.f;
        const bool  m  = (pd > 0.095f) && (ad > 0.095f);
        const float sm = (t >= 1 && t <= 30)
                             ? (zm[(t - 1) * 12 + j] + zm[(t + 1) * 12 + j]) * 0.5f
                             : 0.f;
        zf[i] = m ? sm : zm[t * 12 + j];
    }
    __syncthreads();

    for (int i = tid; i < 31 * 12; i += 64) {
        const int t  = i / 12;
        const int j  = i - t * 12;
        const int o  = j >> 2;
        const int c2 = j & 3;
        const int pb = o * 4 + 2 + (c2 & 1);
        float v;
        if (c2 < 2) v = zf[(t + 1) * 12 + pb] + 1.f;
        else        v = (zf[(t + 1) * 12 + pb] - zf[t * 12 + pb]) * 10.f;
        out[b * 372 + i] = v;
    }
}

extern "C" void kernel_launch(void* const* d_in, const int* in_sizes, int n_in,
                              void* d_out, int out_size, void* d_ws, size_t ws_size,
                              hipStream_t stream) {
    (void)in_sizes; (void)n_in; (void)out_size; (void)ws_size;
    const float* x     = (const float*)d_in[0];
    const float* W_enc = (const float*)d_in[1];
    const float* b_enc = (const float*)d_in[2];
    float* out  = (float*)d_out;

    float* zbuf = (float*)d_ws;                     // 24576 floats
    float* Wt   = zbuf + ROWS * NCOL;               // 147456 floats
    float* part = Wt + NCOL * DIM;                  // 4*24576 floats

    k_tw    <<<(NCOL * DIM) / 256, 256, 0, stream>>>(W_enc, Wt);
    k_gemm  <<<(ROWS / RPB) * KSPL, 256, 0, stream>>>(x, Wt, part);
    k_reduce<<<(ROWS * NCOL) / 256, 256, 0, stream>>>(part, b_enc, zbuf);
    k_post  <<<N_B, 64, 0, stream>>>(zbuf, out);
}

// Round 5
// 174.074 us; speedup vs baseline: 1.0341x; 1.0341x over previous
//
#include <hip/hip_runtime.h>

#define N_B   64
#define T_S   32
#define DIM   12288          // 3*64*64
#define ROWS  2048           // N_B*T_S
#define NCOL  12             // used GEMM columns (3 obj * 4)
#define RPB   16             // rows per block (4 waves x 4 rows)
#define KSPL  8              // split-K factor
#define KSEG  (DIM / KSPL)   // 1536
#define JSTEP (KSEG / 256)   // 6 f4-steps per lane

// ---------------- Kernel 0: transpose used W columns -> Wt[c][k] -----------
__global__ __launch_bounds__(256) void k_tw(const float* __restrict__ W,
                                            float* __restrict__ Wt) {
    const int idx = blockIdx.x * 256 + threadIdx.x;   // 0 .. 147455
    const int c   = idx / DIM;
    const int k   = idx - c * DIM;
    const int cm  = ((c >> 2) << 3) | (c & 3);
    Wt[idx] = W[k * 24 + cm];
}

// ---------------- Kernel 1: split-K skinny GEMM, 16 rows/block -------------
// Grid: 1024 blocks = 128 row-groups x 8 k-segments. Wave w owns rows
// r0..r0+3 and the block's whole k-segment; all 4 waves read the SAME Wt
// addresses (L1 sharing), so Wt L2 traffic = 576KB * 128 * (1/L1reuse).
__global__ __launch_bounds__(256) void k_gemm(const float* __restrict__ x,
                                              const float* __restrict__ Wt,
                                              float* __restrict__ part) {
    const int rb   = blockIdx.x >> 3;      // row group (0..127)
    const int sg   = blockIdx.x & 7;       // k segment (0..7)
    const int tid  = threadIdx.x;
    const int wave = tid >> 6;
    const int lane = tid & 63;
    const int r0   = rb * RPB + wave * 4;  // this wave's first row
    const int kb0  = sg * KSEG + lane * 4;

    float acc[4][NCOL];
#pragma unroll
    for (int r = 0; r < 4; ++r)
#pragma unroll
        for (int c = 0; c < NCOL; ++c) acc[r][c] = 0.f;

#pragma unroll 1
    for (int j = 0; j < JSTEP; ++j) {
        const int kb = kb0 + j * 256;
        float4 wv[NCOL];
#pragma unroll
        for (int c = 0; c < NCOL; ++c)
            wv[c] = *(const float4*)(Wt + (size_t)c * DIM + kb);
        float4 xv[4];
#pragma unroll
        for (int r = 0; r < 4; ++r)
            xv[r] = *(const float4*)(x + (size_t)(r0 + r) * DIM + kb);
#pragma unroll
        for (int r = 0; r < 4; ++r)
#pragma unroll
            for (int c = 0; c < NCOL; ++c)
                acc[r][c] += xv[r].x * wv[c].x + xv[r].y * wv[c].y +
                             xv[r].z * wv[c].z + xv[r].w * wv[c].w;
    }

    // wave butterfly: sum each of the 48 accumulators across 64 lanes
#pragma unroll
    for (int r = 0; r < 4; ++r)
#pragma unroll
        for (int c = 0; c < NCOL; ++c) {
            float v = acc[r][c];
            v += __shfl_xor(v, 32, 64);
            v += __shfl_xor(v, 16, 64);
            v += __shfl_xor(v, 8, 64);
            v += __shfl_xor(v, 4, 64);
            v += __shfl_xor(v, 2, 64);
            v += __shfl_xor(v, 1, 64);
            acc[r][c] = v;
        }

    // waves own disjoint rows -> pure concat through LDS, coalesced store
    __shared__ float red[RPB * NCOL];      // 192 floats, [w*4+r][c]
    if (lane == 0) {
#pragma unroll
        for (int r = 0; r < 4; ++r)
#pragma unroll
            for (int c = 0; c < NCOL; ++c)
                red[(wave * 4 + r) * NCOL + c] = acc[r][c];
    }
    __syncthreads();

    if (tid < RPB * NCOL)
        part[(size_t)sg * (ROWS * NCOL) + (size_t)rb * (RPB * NCOL) + tid] = red[tid];
}

// ---------------- Kernel 2: reduce split-K + bias + sigmoid constrain ------
__global__ __launch_bounds__(256) void k_reduce(const float* __restrict__ part,
                                                const float* __restrict__ b_enc,
                                                float* __restrict__ zbuf) {
    const int rc = blockIdx.x * 256 + threadIdx.x;    // 0..24575 = row*12+c
    float s = 0.f;
#pragma unroll
    for (int i = 0; i < KSPL; ++i) s += part[(size_t)i * (ROWS * NCOL) + rc];

    const int c  = rc % NCOL;
    const int o  = c >> 2;
    const int cp = c & 3;
    s += b_enc[o * 8 + cp];
    const float sg = 1.f / (1.f + expf(-s));
    float v;
    if (cp == 0)      v = sg * 0.7f + 0.1f;
    else if (cp == 1) v = sg * 0.5f + 0.75f;
    else              v = (2.f * sg - 1.f) * 0.9f;
    zbuf[rc] = v;
}

// ---------------- Kernel 3: match + fix_supair + output --------------------
__global__ __launch_bounds__(64) void k_post(const float* __restrict__ zbuf,
                                             float* __restrict__ out) {
    __shared__ float z[T_S * NCOL];
    __shared__ float zm[T_S * NCOL];
    __shared__ float zf[T_S * NCOL];
    __shared__ int   perm[T_S];
    const int b   = blockIdx.x;
    const int tid = threadIdx.x;

#pragma unroll
    for (int i = 0; i < 6; ++i)
        z[tid + 64 * i] = zbuf[b * 384 + tid + 64 * i];
    __syncthreads();

    if (tid == 0) {
        float px0 = z[2],  py0 = z[3];
        float px1 = z[6],  py1 = z[7];
        float px2 = z[10], py2 = z[11];
        for (int t = 1; t < T_S; ++t) {
            const int base = t * 12;
            const float cx0 = z[base + 2],  cy0 = z[base + 3];
            const float cx1 = z[base + 6],  cy1 = z[base + 7];
            const float cx2 = z[base + 10], cy2 = z[base + 11];

            float dx, dy;
            dx = px0 - cx0; dy = py0 - cy0; const float e00 = dx * dx + dy * dy;
            dx = px0 - cx1; dy = py0 - cy1; const float e01 = dx * dx + dy * dy;
            dx = px0 - cx2; dy = py0 - cy2; const float e02 = dx * dx + dy * dy;
            dx = px1 - cx0; dy = py1 - cy0; const float e10 = dx * dx + dy * dy;
            dx = px1 - cx1; dy = py1 - cy1; const float e11 = dx * dx + dy * dy;
            dx = px1 - cx2; dy = py1 - cy2; const float e12 = dx * dx + dy * dy;
            dx = px2 - cx0; dy = py2 - cy0; const float e20 = dx * dx + dy * dy;
            dx = px2 - cx1; dy = py2 - cy1; const float e21 = dx * dx + dy * dy;
            dx = px2 - cx2; dy = py2 - cy2; const float e22 = dx * dx + dy * dy;

            auto amin3 = [](float a0, float a1, float a2) {
                int j = 0; float e = a0;
                if (a1 < e) { e = a1; j = 1; }
                if (a2 < e) { j = 2; }
                return j;
            };
            int i0 = amin3(e00, e01, e02);
            int i1 = amin3(e10, e11, e12);
            int i2 = amin3(e20, e21, e22);
            const bool ok = (i1 != i0) && (i2 != i1) && (i0 != i2);
            if (!ok) {
                float u0 = 0.f, u1 = 0.f, u2 = 0.f;
                i0 = amin3(e00, e01, e02);
                if (i0 == 0) u0 = 1.f; else if (i0 == 1) u1 = 1.f; else u2 = 1.f;
                i1 = amin3(e10 + u0 * 1e12f, e11 + u1 * 1e12f, e12 + u2 * 1e12f);
                if (i1 == 0) u0 = 1.f; else if (i1 == 1) u1 = 1.f; else u2 = 1.f;
                i2 = amin3(e20 + u0 * 1e12f, e21 + u1 * 1e12f, e22 + u2 * 1e12f);
            }
            perm[t] = i0 * 9 + i1 * 3 + i2;
            px0 = (i0 == 0) ? cx0 : (i0 == 1) ? cx1 : cx2;
            py0 = (i0 == 0) ? cy0 : (i0 == 1) ? cy1 : cy2;
            px1 = (i1 == 0) ? cx0 : (i1 == 1) ? cx1 : cx2;
            py1 = (i1 == 0) ? cy0 : (i1 == 1) ? cy1 : cy2;
            px2 = (i2 == 0) ? cx0 : (i2 == 1) ? cx1 : cx2;
            py2 = (i2 == 0) ? cy0 : (i2 == 1) ? cy1 : cy2;
        }
    }
    __syncthreads();

#pragma unroll
    for (int ii = 0; ii < 6; ++ii) {
        const int i  = tid + 64 * ii;
        const int t  = i / 12;
        const int j  = i - t * 12;
        const int k  = j >> 2;
        const int ch = j & 3;
        int p = k;
        if (t > 0) {
            const int code = perm[t];
            p = (k == 0) ? code / 9 : (k == 1) ? (code % 9) / 3 : code % 3;
        }
        zm[i] = z[t * 12 + p * 4 + ch];
    }
    __syncthreads();

#pragma unroll
    for (int ii = 0; ii < 6; ++ii) {
        const int i  = tid + 64 * ii;
        const int t  = i / 12;
        const int j  = i - t * 12;
        const int o  = j >> 2;
        const int cc = j & 1;
        const int mb = o * 4 + cc;
        const float pd = (t >= 1)  ? fabsf(zm[t * 12 + mb] - zm[(t - 1) * 12 + mb]) : 0.f;
        const float ad = (t <= 30) ? fabsf(zm[(t + 1) * 12 + mb] - zm[t * 12 + mb]) : 0.f;
        const bool  m  = (pd > 0.095f) && (ad > 0.095f);
        const float sm = (t >= 1 && t <= 30)
                             ? (zm[(t - 1) * 12 + j] + zm[(t + 1) * 12 + j]) * 0.5f
                             : 0.f;
        zf[i] = m ? sm : zm[t * 12 + j];
    }
    __syncthreads();

    for (int i = tid; i < 31 * 12; i += 64) {
        const int t  = i / 12;
        const int j  = i - t * 12;
        const int o  = j >> 2;
        const int c2 = j & 3;
        const int pb = o * 4 + 2 + (c2 & 1);
        float v;
        if (c2 < 2) v = zf[(t + 1) * 12 + pb] + 1.f;
        else        v = (zf[(t + 1) * 12 + pb] - zf[t * 12 + pb]) * 10.f;
        out[b * 372 + i] = v;
    }
}

extern "C" void kernel_launch(void* const* d_in, const int* in_sizes, int n_in,
                              void* d_out, int out_size, void* d_ws, size_t ws_size,
                              hipStream_t stream) {
    (void)in_sizes; (void)n_in; (void)out_size; (void)ws_size;
    const float* x     = (const float*)d_in[0];
    const float* W_enc = (const float*)d_in[1];
    const float* b_enc = (const float*)d_in[2];
    float* out  = (float*)d_out;

    float* zbuf = (float*)d_ws;                     // 24576 floats
    float* Wt   = zbuf + ROWS * NCOL;               // 147456 floats
    float* part = Wt + NCOL * DIM;                  // 8*24576 floats

    k_tw    <<<(NCOL * DIM) / 256, 256, 0, stream>>>(W_enc, Wt);
    k_gemm  <<<(ROWS / RPB) * KSPL, 256, 0, stream>>>(x, Wt, part);
    k_reduce<<<(ROWS * NCOL) / 256, 256, 0, stream>>>(part, b_enc, zbuf);
    k_post  <<<N_B, 64, 0, stream>>>(zbuf, out);
}